// Round 18
// baseline (242.721 us; speedup 1.0000x reference)
//
#include <hip/hip_runtime.h>
#include <hip/hip_bf16.h>
#include <stdint.h>

typedef __attribute__((ext_vector_type(8))) short bf16x8;
typedef __attribute__((ext_vector_type(4))) float f32x4;
typedef __attribute__((ext_vector_type(4))) unsigned int uint32x4;

#define TOKENS 8192
#define DMODEL 1024
#define NQKV   3072
#define NSEQ   2048
#define NHEAD  16
#define DHEAD  64

__device__ __forceinline__ ushort f32_bf16(float f) {
    uint32_t u = __builtin_bit_cast(uint32_t, f);
    u = (u + 0x7fffu + ((u >> 16) & 1u)) >> 16;
    return (ushort)u;
}

__device__ __forceinline__ unsigned int cvt_pk_bf16(float lo, float hi) {
    unsigned int r;
    asm("v_cvt_pk_bf16_f32 %0, %1, %2" : "=v"(r) : "v"(lo), "v"(hi));
    return r;
}
__device__ __forceinline__ void permlane32_swap(unsigned int& a, unsigned int& b) {
    asm("v_permlane32_swap_b32 %0, %1" : "+v"(a), "+v"(b));
}
__device__ __forceinline__ void permlane16_swap(unsigned int& a, unsigned int& b) {
    asm("v_permlane16_swap_b32 %0, %1" : "+v"(a), "+v"(b));
}
// Opaque register copy: NOT a COPY MachineInstr, so the register coalescer
// cannot merge dst with src (else permlane*_swap self-swaps). [R6 post-mortem]
__device__ __forceinline__ unsigned opaque_copy(unsigned x) {
    unsigned y;
    asm("v_mov_b32 %0, %1" : "=v"(y) : "v"(x));
    return y;
}

// cross-lane reduce over lanes {l, l^16, l^32, l^48} via permlane swaps
__device__ __forceinline__ float red_max_g(float x) {
    unsigned a = __builtin_bit_cast(unsigned, x);
    unsigned b = opaque_copy(a);
    permlane16_swap(a, b);
    float r = fmaxf(__builtin_bit_cast(float, a), __builtin_bit_cast(float, b));
    unsigned c = __builtin_bit_cast(unsigned, r);
    unsigned d = opaque_copy(c);
    permlane32_swap(c, d);
    return fmaxf(__builtin_bit_cast(float, c), __builtin_bit_cast(float, d));
}
__device__ __forceinline__ float red_sum_g(float x) {
    unsigned a = __builtin_bit_cast(unsigned, x);
    unsigned b = opaque_copy(a);
    permlane16_swap(a, b);
    float r = __builtin_bit_cast(float, a) + __builtin_bit_cast(float, b);
    unsigned c = __builtin_bit_cast(unsigned, r);
    unsigned d = opaque_copy(c);
    permlane32_swap(c, d);
    return __builtin_bit_cast(float, c) + __builtin_bit_cast(float, d);
}

// async global->LDS, 16B per lane; LDS dest = wave-uniform base + lane*16
__device__ __forceinline__ void gload16(const void* g, void* l) {
    __builtin_amdgcn_global_load_lds(
        (const __attribute__((address_space(1))) void*)g,
        (__attribute__((address_space(3))) void*)l, 16, 0, 0);
}

// raw barrier with compiler memory fences on both sides
__device__ __forceinline__ void barf() {
    asm volatile("" ::: "memory");
    __builtin_amdgcn_s_barrier();
    asm volatile("" ::: "memory");
}

// Fused input conversion: one launch, three independent jobs run concurrently.
__global__ __launch_bounds__(256) void fused_cvt_kernel(
    const float* __restrict__ x,     ushort* __restrict__ xb,
    const float* __restrict__ wqkv,  ushort* __restrict__ wqkv_t,
    const float* __restrict__ wout,  ushort* __restrict__ wout_t)
{
    __shared__ float tile[64][65];
    const int bid = blockIdx.x;
    const int tid = threadIdx.x;

    if (bid < 8192) {                      // ---- x conversion
        const int i = bid * 256 + tid;
        float4 v = reinterpret_cast<const float4*>(x)[i];
        ushort4 o;
        o.x = f32_bf16(v.x); o.y = f32_bf16(v.y);
        o.z = f32_bf16(v.z); o.w = f32_bf16(v.w);
        reinterpret_cast<ushort4*>(xb)[i] = o;
        return;
    }

    const float* w; ushort* wt; int N, bx, by;
    if (bid < 8960) {                      // ---- w_qkv transpose (48 x 16)
        const int r = bid - 8192;
        w = wqkv; wt = wqkv_t; N = NQKV;
        bx = r % 48; by = r / 48;
    } else {                               // ---- w_out transpose (16 x 16)
        const int r = bid - 8960;
        w = wout; wt = wout_t; N = DMODEL;
        bx = r % 16; by = r / 16;
    }
    const int rr = tid >> 4;               // 0..15
    const int c4 = (tid & 15) * 4;         // 0,4,..,60
    const int n0 = bx * 64;
    const int k0 = by * 64;
    #pragma unroll
    for (int i = 0; i < 4; ++i) {
        const float4 v = *reinterpret_cast<const float4*>(&w[(size_t)(k0 + rr + i * 16) * N + n0 + c4]);
        tile[rr + i * 16][c4 + 0] = v.x;
        tile[rr + i * 16][c4 + 1] = v.y;
        tile[rr + i * 16][c4 + 2] = v.z;
        tile[rr + i * 16][c4 + 3] = v.w;
    }
    __syncthreads();
    #pragma unroll
    for (int i = 0; i < 4; ++i) {
        ushort4 o;
        o.x = f32_bf16(tile[c4 + 0][rr + i * 16]);
        o.y = f32_bf16(tile[c4 + 1][rr + i * 16]);
        o.z = f32_bf16(tile[c4 + 2][rr + i * 16]);
        o.w = f32_bf16(tile[c4 + 3][rr + i * 16]);
        *reinterpret_cast<ushort4*>(&wt[(size_t)(n0 + rr + i * 16) * 1024 + k0 + c4]) = o;
    }
}

// ============ WAVE-PRIVATE barrier-free GEMM =================================
// One wave (64 threads) per block owns a 64x64 output tile with PRIVATE LDS
// (3 x 8KB buffer rotation). Per K-step: counted vmcnt(16) on the wave's OWN
// queue (depth-2 prefetch) -> 8 ds_read_b128 -> lgkmcnt(0)+sched_barrier
// (rule #18) -> stage tile t+3 into the just-consumed buffer -> 16 MFMA.
// ZERO s_barrier anywhere: no convoy, waves free-run; race-free since each
// wave only touches its own LDS. T1 XCD row-chunk swizzle for L2-resident A.
// Cost: A/B staged per 64-tile (2x L2 traffic vs 128^2 shared staging).
template<int MODE, int NX>
__global__ __launch_bounds__(64) void gemm_wp(
    const ushort* __restrict__ A, const ushort* __restrict__ Bt,
    ushort* __restrict__ Qb, ushort* __restrict__ Kb, ushort* __restrict__ Vtb,
    float* __restrict__ Out, const float* __restrict__ bias)
{
    constexpr int K = 1024;
    __shared__ __align__(16) ushort As[3][64 * 32];
    __shared__ __align__(16) ushort Bs[3][64 * 32];

    const int lane = threadIdx.x;          // 0..63
    const int l16  = lane & 15;
    const int g    = lane >> 4;

    // XCD row-chunk swizzle (grid divisible by 8)
    const int nwg   = (int)gridDim.x;
    const int chunk = nwg >> 3;
    const int swz   = (blockIdx.x & 7) * chunk + ((int)blockIdx.x >> 3);
    const int row0  = (swz / NX) * 64;
    const int col0  = (swz % NX) * 64;

    // staging: lane covers row srow (+16/+32/+48), swizzled 16B quad
    const int srow  = lane >> 2;
    const int sswz8 = ((lane & 3) ^ ((lane >> 3) & 3)) * 8;
    const ushort* Ag = A  + (size_t)(row0 + srow) * K + sswz8;
    const ushort* Bg = Bt + (size_t)(col0 + srow) * K + sswz8;

    const int cq8 = (g ^ ((l16 >> 1) & 3)) * 8;   // read-side swizzle

    f32x4 acc[4][4] = {};

#define WSTAGE(T) do { const int _b = (T) % 3; const int _k = (T) * 32;  \
        gload16(Ag + _k,           &As[_b][0]);                          \
        gload16(Ag + 16 * K + _k,  &As[_b][512]);                        \
        gload16(Ag + 32 * K + _k,  &As[_b][1024]);                       \
        gload16(Ag + 48 * K + _k,  &As[_b][1536]);                       \
        gload16(Bg + _k,           &Bs[_b][0]);                          \
        gload16(Bg + 16 * K + _k,  &Bs[_b][512]);                        \
        gload16(Bg + 32 * K + _k,  &Bs[_b][1024]);                       \
        gload16(Bg + 48 * K + _k,  &Bs[_b][1536]);                       \
    } while (0)

#define WBODY(T, DOSTAGE) do {                                           \
        const int _buf = (T) % 3;                                        \
        bf16x8 a[4], b[4];                                               \
        _Pragma("unroll")                                                \
        for (int m = 0; m < 4; ++m)                                      \
            a[m] = *reinterpret_cast<const bf16x8*>(                     \
                &As[_buf][(m * 16 + l16) * 32 + cq8]);                   \
        _Pragma("unroll")                                                \
        for (int n = 0; n < 4; ++n)                                      \
            b[n] = *reinterpret_cast<const bf16x8*>(                     \
                &Bs[_buf][(n * 16 + l16) * 32 + cq8]);                   \
        asm volatile("s_waitcnt lgkmcnt(0)" ::: "memory");               \
        __builtin_amdgcn_sched_barrier(0);                               \
        if (DOSTAGE) WSTAGE((T) + 3);                                    \
        __builtin_amdgcn_s_setprio(1);                                   \
        _Pragma("unroll")                                                \
        for (int m = 0; m < 4; ++m)                                      \
            _Pragma("unroll")                                            \
            for (int n = 0; n < 4; ++n)                                  \
                acc[m][n] = __builtin_amdgcn_mfma_f32_16x16x32_bf16(     \
                    a[m], b[n], acc[m][n], 0, 0, 0);                     \
        __builtin_amdgcn_s_setprio(0);                                   \
    } while (0)

    WSTAGE(0); WSTAGE(1); WSTAGE(2);       // 24 loads outstanding
    for (int t = 0; t < 29; ++t) {         // stage t+3 each iter
        asm volatile("s_waitcnt vmcnt(16)" ::: "memory");  // tile t landed
        WBODY(t, true);
    }
    asm volatile("s_waitcnt vmcnt(16)" ::: "memory");
    WBODY(29, false);
    asm volatile("s_waitcnt vmcnt(8)" ::: "memory");
    WBODY(30, false);
    asm volatile("s_waitcnt vmcnt(0)" ::: "memory");
    WBODY(31, false);
#undef WSTAGE
#undef WBODY

    if (MODE == 0) {
        const int part = col0 >> 10;                    // 0=Q 1=K 2=V (uniform per block)
        const float QSC = 0.18033688011112042f;         // DIM_HEAD^-0.5 * log2(e)
        #pragma unroll
        for (int m = 0; m < 4; ++m) {
            const int trow = row0 + m * 16 + 4 * g;
            #pragma unroll
            for (int n = 0; n < 4; ++n) {
                const int c  = col0 + n * 16 + l16;
                const int cc = c & 1023;
                const int h  = cc >> 6, d = cc & 63;
                #pragma unroll
                for (int jj = 0; jj < 4; ++jj) {
                    const int t  = trow + jj;
                    const int bb = t >> 11, nn = t & 2047;
                    const float v = acc[m][n][jj];
                    const size_t bhid = (size_t)(bb * NHEAD + h);
                    if (part == 0)
                        Qb[(bhid * NSEQ + nn) * DHEAD + d] = f32_bf16(v * QSC);
                    else if (part == 1)
                        Kb[(bhid * NSEQ + nn) * DHEAD + d] = f32_bf16(v);
                    else  // V^T tiled: [bh][n/32][d:64][n%32]
                        Vtb[bhid * (NSEQ * DHEAD) + (size_t)(nn >> 5) * (DHEAD * 32)
                            + d * 32 + (nn & 31)] = f32_bf16(v);
                }
            }
        }
    } else {
        #pragma unroll
        for (int m = 0; m < 4; ++m) {
            const int trow = row0 + m * 16 + 4 * g;
            #pragma unroll
            for (int n = 0; n < 4; ++n) {
                const int c = col0 + n * 16 + l16;
                const float bv = bias[c];
                #pragma unroll
                for (int jj = 0; jj < 4; ++jj)
                    Out[(size_t)(trow + jj) * DMODEL + c] = acc[m][n][jj] + bv;
            }
        }
    }
}

// QK^T (swapped) + online softmax for one 16-row q-tile against a 64-key LDS
// tile. Lane(l16,g) holds S[key=16t+4g+jj][q=l16].
__device__ __forceinline__ void attn_qk(
    int kt, int qr0s, int l16, int g,
    const bf16x8 (&kk)[4][2],
    const bf16x8 qf0, const bf16x8 qf1,
    f32x4 (&oacc)[4], float& mrun, float& lsum,
    bf16x8& pf0, bf16x8& pf1)
{
    const f32x4 zero = {};
    f32x4 s[4];
    __builtin_amdgcn_s_setprio(1);
    #pragma unroll
    for (int t = 0; t < 4; ++t) {
        s[t] = __builtin_amdgcn_mfma_f32_16x16x32_bf16(kk[t][0], qf0, zero, 0, 0, 0);
        s[t] = __builtin_amdgcn_mfma_f32_16x16x32_bf16(kk[t][1], qf1, s[t], 0, 0, 0);
    }
    __builtin_amdgcn_s_setprio(0);
    if (kt + 63 > qr0s) {                               // diagonal tiles only
        const int kb = kt + 4 * g - (qr0s + l16);       // key - q = kb + 16t + jj
        #pragma unroll
        for (int t = 0; t < 4; ++t)
            #pragma unroll
            for (int jj = 0; jj < 4; ++jj)
                if (kb + 16 * t + jj > 0) s[t][jj] = -1e30f;
    }
    const float m0 = fmaxf(fmaxf(s[0][0], s[0][1]), s[0][2]);
    const float m1 = fmaxf(fmaxf(s[0][3], s[1][0]), s[1][1]);
    const float m2 = fmaxf(fmaxf(s[1][2], s[1][3]), s[2][0]);
    const float m3 = fmaxf(fmaxf(s[2][1], s[2][2]), s[2][3]);
    const float m4 = fmaxf(fmaxf(s[3][0], s[3][1]), s[3][2]);
    const float m5 = fmaxf(fmaxf(m0, m1), m2);
    const float m6 = fmaxf(fmaxf(m3, m4), s[3][3]);
    const float mxl = fmaxf(m5, m6);                    // in-lane max (16 vals)
    if (__any(mxl > mrun + 8.0f)) {
        const float mx = red_max_g(mxl);                // cross-lane only here
        const float mn = fmaxf(mrun, mx);
        const float sc = __builtin_amdgcn_exp2f(mrun - mn);
        mrun = mn;
        lsum *= sc;                                     // per-lane partial
        float scj[4];
        #pragma unroll
        for (int jj = 0; jj < 4; ++jj) scj[jj] = __shfl(sc, 4 * g + jj);
        #pragma unroll
        for (int dt = 0; dt < 4; ++dt)
            #pragma unroll
            for (int jj = 0; jj < 4; ++jj) oacc[dt][jj] *= scj[jj];
    }
    float ps = 0.f;
    unsigned int pw[4][2];
    #pragma unroll
    for (int t = 0; t < 4; ++t) {
        const float p0 = __builtin_amdgcn_exp2f(s[t][0] - mrun);
        const float p1 = __builtin_amdgcn_exp2f(s[t][1] - mrun);
        const float p2 = __builtin_amdgcn_exp2f(s[t][2] - mrun);
        const float p3 = __builtin_amdgcn_exp2f(s[t][3] - mrun);
        ps += (p0 + p1) + (p2 + p3);
        pw[t][0] = cvt_pk_bf16(p0, p1);
        pw[t][1] = cvt_pk_bf16(p2, p3);
    }
    lsum += ps;                                         // per-lane partial sum
    unsigned int a0 = pw[0][0], a1 = pw[0][1], b0 = pw[1][0], b1 = pw[1][1];
    permlane32_swap(a0, b0); permlane32_swap(a1, b1);
    permlane16_swap(a0, b0); permlane16_swap(a1, b1);
    pf0 = __builtin_bit_cast(bf16x8, (uint32x4){a0, a1, b0, b1});
    unsigned int c0 = pw[2][0], c1 = pw[2][1], d0 = pw[3][0], d1 = pw[3][1];
    permlane32_swap(c0, d0); permlane32_swap(c1, d1);
    permlane16_swap(c0, d0); permlane16_swap(c1, d1);
    pf1 = __builtin_bit_cast(bf16x8, (uint32x4){c0, c1, d0, d1});
}

// Causal flash attention. 1024 blocks (XCD-swizzled). 4 waves/block; each wave
// owns TWO 16-row q-tiles from complementary q-blocks {j, 31-j}. K/V 64-key
// tiles staged into double-buffered LDS via global_load_lds (swizzled source);
// 2-phase pipeline, 1 barrier/iter.
__global__ __launch_bounds__(256) void attn_kernel(
    const ushort* __restrict__ Qb, const ushort* __restrict__ Kb,
    const ushort* __restrict__ Vt, ushort* __restrict__ Ob)
{
    __shared__ __align__(16) ushort Klds[2][4096];
    __shared__ __align__(16) ushort Vlds[2][4096];

    const int lane = threadIdx.x & 63;
    const int w    = threadIdx.x >> 6;
    const int l16  = lane & 15;
    const int g    = lane >> 4;

    const int bid = blockIdx.x;
    const int xcd = bid & 7, ii = bid >> 3;
    const int bh  = xcd * 8 + (ii >> 4);               // 8 (b,h) per XCD
    const int jlo = ii & 15;
    const int jhi = 31 - jlo;

    const int qr0_lo = jlo * 64 + w * 16;
    const int qr0_hi = jhi * 64 + w * 16;
    const int nt = jhi + 1;                            // 64-key tiles

    const ushort* QpL = Qb + ((size_t)bh * NSEQ + qr0_lo + l16) * DHEAD + 8 * g;
    const ushort* QpH = Qb + ((size_t)bh * NSEQ + qr0_hi + l16) * DHEAD + 8 * g;
    const bf16x8 qfL0 = *reinterpret_cast<const bf16x8*>(QpL);
    const bf16x8 qfL1 = *reinterpret_cast<const bf16x8*>(QpL + 32);
    const bf16x8 qfH0 = *reinterpret_cast<const bf16x8*>(QpH);
    const bf16x8 qfH1 = *reinterpret_cast<const bf16x8*>(QpH + 32);

    const ushort* Kg = Kb + (size_t)bh * (NSEQ * DHEAD);
    const ushort* Vg = Vt + (size_t)bh * (NSEQ * DHEAD);

    const int q0    = w * 2;
    const int srow  = lane >> 2;
    const int sswz8 = ((lane & 3) ^ ((lane >> 3) & 3)) * 8;
    const int cq8   = (g ^ ((l16 >> 1) & 3)) * 8;

    f32x4 oaccL[4] = {}, oaccH[4] = {};
    float mrunL = -1e30f, lsumL = 0.f, mrunH = -1e30f, lsumH = 0.f;

    #pragma unroll
    for (int i = 0; i < 2; ++i) {
        const int q = q0 + i;
        gload16(Kg + (size_t)((q & 3) * 16 + srow) * 64 + (q >> 2) * 32 + sswz8,
                &Klds[0][q * 512]);
        gload16(Vg + (size_t)(q >> 2) * 2048 + ((q & 3) * 16 + srow) * 32 + sswz8,
                &Vlds[0][q * 512]);
    }
    __syncthreads();

    for (int t = 0; t < nt; ++t) {
        const int cur = t & 1;
        if (t + 1 < nt) {
            const int kt1 = (t + 1) * 64;
            #pragma unroll
            for (int i = 0; i < 2; ++i) {
                const int q = q0 + i;
                gload16(Kg + (size_t)(kt1 + (q & 3) * 16 + srow) * 64 + (q >> 2) * 32 + sswz8,
                        &Klds[cur ^ 1][q * 512]);
                gload16(Vg + (size_t)kt1 * 64 + (q >> 2) * 2048 + ((q & 3) * 16 + srow) * 32 + sswz8,
                        &Vlds[cur ^ 1][q * 512]);
            }
        }
        const int kt = t * 64;
        bf16x8 kk[4][2];
        #pragma unroll
        for (int tt = 0; tt < 4; ++tt) {
            #pragma unroll
            for (int h = 0; h < 2; ++h)
                kk[tt][h] = *reinterpret_cast<const bf16x8*>(
                    &Klds[cur][h * 2048 + (16 * tt + l16) * 32 + cq8]);
        }
        bf16x8 pfH0, pfH1, pfL0, pfL1;
        attn_qk(kt, qr0_hi, l16, g, kk, qfH0, qfH1, oaccH, mrunH, lsumH, pfH0, pfH1);
        const bool doLo = (t <= jlo);
        if (doLo)
            attn_qk(kt, qr0_lo, l16, g, kk, qfL0, qfL1, oaccL, mrunL, lsumL, pfL0, pfL1);
        __builtin_amdgcn_s_setprio(1);
        #pragma unroll
        for (int dt = 0; dt < 4; ++dt) {
            const bf16x8 v0 = *reinterpret_cast<const bf16x8*>(
                &Vlds[cur][(dt * 16 + l16) * 32 + cq8]);
            const bf16x8 v1 = *reinterpret_cast<const bf16x8*>(
                &Vlds[cur][2048 + (dt * 16 + l16) * 32 + cq8]);
            oaccH[dt] = __builtin_amdgcn_mfma_f32_16x16x32_bf16(pfH0, v0, oaccH[dt], 0, 0, 0);
            oaccH[dt] = __builtin_amdgcn_mfma_f32_16x16x32_bf16(pfH1, v1, oaccH[dt], 0, 0, 0);
            if (doLo) {
                oaccL[dt] = __builtin_amdgcn_mfma_f32_16x16x32_bf16(pfL0, v0, oaccL[dt], 0, 0, 0);
                oaccL[dt] = __builtin_amdgcn_mfma_f32_16x16x32_bf16(pfL1, v1, oaccL[dt], 0, 0, 0);
            }
        }
        __builtin_amdgcn_s_setprio(0);
        __syncthreads();
    }

    const int bb = bh >> 4, h = bh & 15;
    {
        const float inv = 1.0f / red_sum_g(lsumH);     // cross-lane sum here
        float invj[4];
        #pragma unroll
        for (int jj = 0; jj < 4; ++jj) invj[jj] = __shfl(inv, 4 * g + jj);
        #pragma unroll
        for (int jj = 0; jj < 4; ++jj) {
            const size_t t = (size_t)bb * NSEQ + qr0_hi + 4 * g + jj;
            #pragma unroll
            for (int dt = 0; dt < 4; ++dt)
                Ob[t * DMODEL + h * DHEAD + dt * 16 + l16] = f32_bf16(oaccH[dt][jj] * invj[jj]);
        }
    }
    {
        const float inv = 1.0f / red_sum_g(lsumL);
        float invj[4];
        #pragma unroll
        for (int jj = 0; jj < 4; ++jj) invj[jj] = __shfl(inv, 4 * g + jj);
        #pragma unroll
        for (int jj = 0; jj < 4; ++jj) {
            const size_t t = (size_t)bb * NSEQ + qr0_lo + 4 * g + jj;
            #pragma unroll
            for (int dt = 0; dt < 4; ++dt)
                Ob[t * DMODEL + h * DHEAD + dt * 16 + l16] = f32_bf16(oaccL[dt][jj] * invj[jj]);
        }
    }
}

extern "C" void kernel_launch(void* const* d_in, const int* in_sizes, int n_in,
                              void* d_out, int out_size, void* d_ws, size_t ws_size,
                              hipStream_t stream)
{
    const float* x     = (const float*)d_in[0];
    const float* w_qkv = (const float*)d_in[1];
    const float* w_out = (const float*)d_in[2];
    const float* b_out = (const float*)d_in[3];
    float* out = (float*)d_out;

    char* ws = (char*)d_ws;
    ushort* x_bf   = (ushort*)(ws);                    // 16,777,216  (reused as attn out)
    ushort* wqkv_t = (ushort*)(ws + 16777216);         //  6,291,456
    ushort* wout_t = (ushort*)(ws + 23068672);         //  2,097,152
    ushort* q_bf   = (ushort*)(ws + 25165824);         // 16,777,216
    ushort* k_bf   = (ushort*)(ws + 41943040);         // 16,777,216
    ushort* vt_bf  = (ushort*)(ws + 58720256);         // 16,777,216 (V^T tiled)
    ushort* attn_bf = x_bf;

    fused_cvt_kernel<<<dim3(9216), dim3(256), 0, stream>>>(
        x, x_bf, w_qkv, wqkv_t, w_out, wout_t);

    gemm_wp<0, NQKV / 64><<<dim3((NQKV / 64) * (TOKENS / 64)), dim3(64), 0, stream>>>(
        x_bf, wqkv_t, q_bf, k_bf, vt_bf, nullptr, nullptr);

    attn_kernel<<<dim3(1024), dim3(256), 0, stream>>>(q_bf, k_bf, vt_bf, attn_bf);

    gemm_wp<1, DMODEL / 64><<<dim3((DMODEL / 64) * (TOKENS / 64)), dim3(64), 0, stream>>>(
        attn_bf, wout_t, nullptr, nullptr, nullptr, out, b_out);
}

// Round 19
// 205.598 us; speedup vs baseline: 1.1806x; 1.1806x over previous
//
#include <hip/hip_runtime.h>
#include <hip/hip_bf16.h>
#include <stdint.h>

typedef __attribute__((ext_vector_type(8))) short bf16x8;
typedef __attribute__((ext_vector_type(4))) float f32x4;
typedef __attribute__((ext_vector_type(4))) unsigned int uint32x4;

#define TOKENS 8192
#define DMODEL 1024
#define NQKV   3072
#define NSEQ   2048
#define NHEAD  16
#define DHEAD  64

__device__ __forceinline__ ushort f32_bf16(float f) {
    uint32_t u = __builtin_bit_cast(uint32_t, f);
    u = (u + 0x7fffu + ((u >> 16) & 1u)) >> 16;
    return (ushort)u;
}

__device__ __forceinline__ unsigned int cvt_pk_bf16(float lo, float hi) {
    unsigned int r;
    asm("v_cvt_pk_bf16_f32 %0, %1, %2" : "=v"(r) : "v"(lo), "v"(hi));
    return r;
}
__device__ __forceinline__ void permlane32_swap(unsigned int& a, unsigned int& b) {
    asm("v_permlane32_swap_b32 %0, %1" : "+v"(a), "+v"(b));
}
__device__ __forceinline__ void permlane16_swap(unsigned int& a, unsigned int& b) {
    asm("v_permlane16_swap_b32 %0, %1" : "+v"(a), "+v"(b));
}
// Opaque register copy: NOT a COPY MachineInstr, so the register coalescer
// cannot merge dst with src (else permlane*_swap self-swaps). [R6 post-mortem]
__device__ __forceinline__ unsigned opaque_copy(unsigned x) {
    unsigned y;
    asm("v_mov_b32 %0, %1" : "=v"(y) : "v"(x));
    return y;
}

// cross-lane reduce over lanes {l, l^16, l^32, l^48} via permlane swaps
__device__ __forceinline__ float red_max_g(float x) {
    unsigned a = __builtin_bit_cast(unsigned, x);
    unsigned b = opaque_copy(a);
    permlane16_swap(a, b);
    float r = fmaxf(__builtin_bit_cast(float, a), __builtin_bit_cast(float, b));
    unsigned c = __builtin_bit_cast(unsigned, r);
    unsigned d = opaque_copy(c);
    permlane32_swap(c, d);
    return fmaxf(__builtin_bit_cast(float, c), __builtin_bit_cast(float, d));
}
__device__ __forceinline__ float red_sum_g(float x) {
    unsigned a = __builtin_bit_cast(unsigned, x);
    unsigned b = opaque_copy(a);
    permlane16_swap(a, b);
    float r = __builtin_bit_cast(float, a) + __builtin_bit_cast(float, b);
    unsigned c = __builtin_bit_cast(unsigned, r);
    unsigned d = opaque_copy(c);
    permlane32_swap(c, d);
    return __builtin_bit_cast(float, c) + __builtin_bit_cast(float, d);
}

// async global->LDS, 16B per lane; LDS dest = wave-uniform base + lane*16
__device__ __forceinline__ void gload16(const void* g, void* l) {
    __builtin_amdgcn_global_load_lds(
        (const __attribute__((address_space(1))) void*)g,
        (__attribute__((address_space(3))) void*)l, 16, 0, 0);
}

// raw barrier with compiler memory fences on both sides
__device__ __forceinline__ void barf() {
    asm volatile("" ::: "memory");
    __builtin_amdgcn_s_barrier();
    asm volatile("" ::: "memory");
}

// Fused input conversion: one launch, three independent jobs run concurrently.
//   blocks [0, 8192)        : x [8192][1024] f32 -> bf16 (f32x4 per thread)
//   blocks [8192, 8960)     : w_qkv [1024][3072] -> wt [3072][1024] (64x64 tiles)
//   blocks [8960, 9216)     : w_out [1024][1024] -> wt [1024][1024]
__global__ __launch_bounds__(256) void fused_cvt_kernel(
    const float* __restrict__ x,     ushort* __restrict__ xb,
    const float* __restrict__ wqkv,  ushort* __restrict__ wqkv_t,
    const float* __restrict__ wout,  ushort* __restrict__ wout_t)
{
    __shared__ float tile[64][65];
    const int bid = blockIdx.x;
    const int tid = threadIdx.x;

    if (bid < 8192) {                      // ---- x conversion
        const int i = bid * 256 + tid;
        float4 v = reinterpret_cast<const float4*>(x)[i];
        ushort4 o;
        o.x = f32_bf16(v.x); o.y = f32_bf16(v.y);
        o.z = f32_bf16(v.z); o.w = f32_bf16(v.w);
        reinterpret_cast<ushort4*>(xb)[i] = o;
        return;
    }

    const float* w; ushort* wt; int N, bx, by;
    if (bid < 8960) {                      // ---- w_qkv transpose (48 x 16)
        const int r = bid - 8192;
        w = wqkv; wt = wqkv_t; N = NQKV;
        bx = r % 48; by = r / 48;
    } else {                               // ---- w_out transpose (16 x 16)
        const int r = bid - 8960;
        w = wout; wt = wout_t; N = DMODEL;
        bx = r % 16; by = r / 16;
    }
    const int rr = tid >> 4;               // 0..15
    const int c4 = (tid & 15) * 4;         // 0,4,..,60
    const int n0 = bx * 64;
    const int k0 = by * 64;
    #pragma unroll
    for (int i = 0; i < 4; ++i) {
        const float4 v = *reinterpret_cast<const float4*>(&w[(size_t)(k0 + rr + i * 16) * N + n0 + c4]);
        tile[rr + i * 16][c4 + 0] = v.x;
        tile[rr + i * 16][c4 + 1] = v.y;
        tile[rr + i * 16][c4 + 2] = v.z;
        tile[rr + i * 16][c4 + 3] = v.w;
    }
    __syncthreads();
    #pragma unroll
    for (int i = 0; i < 4; ++i) {
        ushort4 o;
        o.x = f32_bf16(tile[c4 + 0][rr + i * 16]);
        o.y = f32_bf16(tile[c4 + 1][rr + i * 16]);
        o.z = f32_bf16(tile[c4 + 2][rr + i * 16]);
        o.w = f32_bf16(tile[c4 + 3][rr + i * 16]);
        *reinterpret_cast<ushort4*>(&wt[(size_t)(n0 + rr + i * 16) * 1024 + k0 + c4]) = o;
    }
}

// C = A[M][1024] @ Bt[N][1024]^T. 128x128 tile, BK=32, double-buffered
// global_load_lds staging (swizzled source) with COUNTED vmcnt (T4).
// 1D grid + bijective XCD row-chunk swizzle (T1). NX = col-panel count.
// MODE 0: scatter to Q (scaled), K, V^T(tiled) bf16. MODE 1: f32 out + bias.
template<int MODE, int NX>
__global__ __launch_bounds__(256) void gemm_bt(
    const ushort* __restrict__ A, const ushort* __restrict__ Bt,
    ushort* __restrict__ Qb, ushort* __restrict__ Kb, ushort* __restrict__ Vtb,
    float* __restrict__ Out, const float* __restrict__ bias)
{
    constexpr int K = 1024;
    __shared__ __align__(16) ushort As[2][128 * 32];
    __shared__ __align__(16) ushort Bs[2][128 * 32];

    const int lane = threadIdx.x & 63;
    const int w    = threadIdx.x >> 6;
    const int l16  = lane & 15;
    const int g    = lane >> 4;

    // XCD row-chunk swizzle (grid is NX*NY, NY multiple of 8)
    const int nwg  = (int)gridDim.x;
    const int chunk = nwg >> 3;                                // per-XCD blocks
    const int swz  = (blockIdx.x & 7) * chunk + ((int)blockIdx.x >> 3);
    const int row0 = (swz / NX) * 128;
    const int col0 = (swz % NX) * 128;

    const int wr   = (w >> 1) * 64;
    const int wc   = (w & 1) * 64;

    // staging map: lane l of wave w -> tile row w*16 + l/4, swizzled 16B quad
    const int srow  = w * 16 + (lane >> 2);
    const int sswz8 = ((lane & 3) ^ ((lane >> 3) & 3)) * 8;   // source col swizzle
    const ushort* Ag = A  + (size_t)(row0 + srow) * K + sswz8;
    const ushort* Bg = Bt + (size_t)(col0 + srow) * K + sswz8;
    const int woff = w * (16 * 32);

    const int cq8 = (g ^ ((l16 >> 1) & 3)) * 8;               // read-side swizzle

    f32x4 acc[4][4] = {};

#define GSTAGE(BUF, KK) do {                                             \
        gload16(Ag + (KK),          &As[BUF][woff]);                     \
        gload16(Ag + 64 * K + (KK), &As[BUF][woff + 64 * 32]);           \
        gload16(Bg + (KK),          &Bs[BUF][woff]);                     \
        gload16(Bg + 64 * K + (KK), &Bs[BUF][woff + 64 * 32]);           \
    } while (0)

#define GCOMPUTE(BUF) do {                                               \
        bf16x8 a[4], b[4];                                               \
        _Pragma("unroll")                                                \
        for (int m = 0; m < 4; ++m)                                      \
            a[m] = *reinterpret_cast<const bf16x8*>(                     \
                &As[BUF][(wr + m * 16 + l16) * 32 + cq8]);               \
        _Pragma("unroll")                                                \
        for (int n = 0; n < 4; ++n)                                      \
            b[n] = *reinterpret_cast<const bf16x8*>(                     \
                &Bs[BUF][(wc + n * 16 + l16) * 32 + cq8]);               \
        _Pragma("unroll")                                                \
        for (int m = 0; m < 4; ++m)                                      \
            _Pragma("unroll")                                            \
            for (int n = 0; n < 4; ++n)                                  \
                acc[m][n] = __builtin_amdgcn_mfma_f32_16x16x32_bf16(     \
                    a[m], b[n], acc[m][n], 0, 0, 0);                     \
    } while (0)

    GSTAGE(0, 0);
    GSTAGE(1, 32);                           // 8 loads outstanding
    for (int kk = 0; kk + 128 <= K; kk += 64) {
        asm volatile("s_waitcnt vmcnt(4)" ::: "memory");   // buf0's 4 done
        barf();
        GCOMPUTE(0);
        barf();                               // everyone done reading buf0
        GSTAGE(0, kk + 64);                   // back to 8 outstanding
        asm volatile("s_waitcnt vmcnt(4)" ::: "memory");   // buf1's 4 done
        barf();
        GCOMPUTE(1);
        barf();
        GSTAGE(1, kk + 96);
    }
    // tail: tiles K-64 (buf0) and K-32 (buf1), 8 outstanding on entry
    asm volatile("s_waitcnt vmcnt(4)" ::: "memory");
    barf();
    GCOMPUTE(0);
    asm volatile("s_waitcnt vmcnt(0)" ::: "memory");
    barf();
    GCOMPUTE(1);
#undef GSTAGE
#undef GCOMPUTE

    if (MODE == 0) {
        const int part = col0 >> 10;                    // 0=Q 1=K 2=V (uniform per block)
        const float QSC = 0.18033688011112042f;         // DIM_HEAD^-0.5 * log2(e)
        #pragma unroll
        for (int m = 0; m < 4; ++m) {
            const int trow = row0 + wr + m * 16 + 4 * g;
            #pragma unroll
            for (int n = 0; n < 4; ++n) {
                const int c  = col0 + wc + n * 16 + l16;
                const int cc = c & 1023;
                const int h  = cc >> 6, d = cc & 63;
                #pragma unroll
                for (int jj = 0; jj < 4; ++jj) {
                    const int t  = trow + jj;
                    const int bb = t >> 11, nn = t & 2047;
                    const float v = acc[m][n][jj];
                    const size_t bhid = (size_t)(bb * NHEAD + h);
                    if (part == 0)
                        Qb[(bhid * NSEQ + nn) * DHEAD + d] = f32_bf16(v * QSC);
                    else if (part == 1)
                        Kb[(bhid * NSEQ + nn) * DHEAD + d] = f32_bf16(v);
                    else  // V^T tiled: [bh][n/32][d:64][n%32]
                        Vtb[bhid * (NSEQ * DHEAD) + (size_t)(nn >> 5) * (DHEAD * 32)
                            + d * 32 + (nn & 31)] = f32_bf16(v);
                }
            }
        }
    } else {
        #pragma unroll
        for (int m = 0; m < 4; ++m) {
            const int trow = row0 + wr + m * 16 + 4 * g;
            #pragma unroll
            for (int n = 0; n < 4; ++n) {
                const int c = col0 + wc + n * 16 + l16;
                const float bv = bias[c];
                #pragma unroll
                for (int jj = 0; jj < 4; ++jj)
                    Out[(size_t)(trow + jj) * DMODEL + c] = acc[m][n][jj] + bv;
            }
        }
    }
}

// QK^T (swapped) + online softmax for one 16-row q-tile against a 64-key LDS
// tile. Lane(l16,g) holds S[key=16t+4g+jj][q=l16].
// Cross-lane red_max only inside the rare rescale branch; lsum is a per-lane
// partial (sc is group-uniform) -> cross-lane red_sum once at epilogue.
__device__ __forceinline__ void attn_qk(
    int kt, int qr0s, int l16, int g,
    const bf16x8 (&kk)[4][2],
    const bf16x8 qf0, const bf16x8 qf1,
    f32x4 (&oacc)[4], float& mrun, float& lsum,
    bf16x8& pf0, bf16x8& pf1)
{
    const f32x4 zero = {};
    f32x4 s[4];
    __builtin_amdgcn_s_setprio(1);
    #pragma unroll
    for (int t = 0; t < 4; ++t) {
        s[t] = __builtin_amdgcn_mfma_f32_16x16x32_bf16(kk[t][0], qf0, zero, 0, 0, 0);
        s[t] = __builtin_amdgcn_mfma_f32_16x16x32_bf16(kk[t][1], qf1, s[t], 0, 0, 0);
    }
    __builtin_amdgcn_s_setprio(0);
    if (kt + 63 > qr0s) {                               // diagonal tiles only
        const int kb = kt + 4 * g - (qr0s + l16);       // key - q = kb + 16t + jj
        #pragma unroll
        for (int t = 0; t < 4; ++t)
            #pragma unroll
            for (int jj = 0; jj < 4; ++jj)
                if (kb + 16 * t + jj > 0) s[t][jj] = -1e30f;
    }
    // in-lane max tree shaped for v_max3 fusion (16 values -> 8 ops)
    const float m0 = fmaxf(fmaxf(s[0][0], s[0][1]), s[0][2]);
    const float m1 = fmaxf(fmaxf(s[0][3], s[1][0]), s[1][1]);
    const float m2 = fmaxf(fmaxf(s[1][2], s[1][3]), s[2][0]);
    const float m3 = fmaxf(fmaxf(s[2][1], s[2][2]), s[2][3]);
    const float m4 = fmaxf(fmaxf(s[3][0], s[3][1]), s[3][2]);
    const float m5 = fmaxf(fmaxf(m0, m1), m2);
    const float m6 = fmaxf(fmaxf(m3, m4), s[3][3]);
    const float mxl = fmaxf(m5, m6);                    // in-lane max (16 vals)
    if (__any(mxl > mrun + 8.0f)) {
        const float mx = red_max_g(mxl);                // cross-lane only here
        const float mn = fmaxf(mrun, mx);
        const float sc = __builtin_amdgcn_exp2f(mrun - mn);
        mrun = mn;
        lsum *= sc;                                     // per-lane partial
        float scj[4];
        #pragma unroll
        for (int jj = 0; jj < 4; ++jj) scj[jj] = __shfl(sc, 4 * g + jj);
        #pragma unroll
        for (int dt = 0; dt < 4; ++dt)
            #pragma unroll
            for (int jj = 0; jj < 4; ++jj) oacc[dt][jj] *= scj[jj];
    }
    float ps = 0.f;
    unsigned int pw[4][2];
    #pragma unroll
    for (int t = 0; t < 4; ++t) {
        const float p0 = __builtin_amdgcn_exp2f(s[t][0] - mrun);
        const float p1 = __builtin_amdgcn_exp2f(s[t][1] - mrun);
        const float p2 = __builtin_amdgcn_exp2f(s[t][2] - mrun);
        const float p3 = __builtin_amdgcn_exp2f(s[t][3] - mrun);
        ps += (p0 + p1) + (p2 + p3);
        pw[t][0] = cvt_pk_bf16(p0, p1);
        pw[t][1] = cvt_pk_bf16(p2, p3);
    }
    lsum += ps;                                         // per-lane partial sum
    // relayout to PV A-fragment via permlane32/16 swaps (distinct defs ->
    // no coalescing hazard)
    unsigned int a0 = pw[0][0], a1 = pw[0][1], b0 = pw[1][0], b1 = pw[1][1];
    permlane32_swap(a0, b0); permlane32_swap(a1, b1);
    permlane16_swap(a0, b0); permlane16_swap(a1, b1);
    pf0 = __builtin_bit_cast(bf16x8, (uint32x4){a0, a1, b0, b1});
    unsigned int c0 = pw[2][0], c1 = pw[2][1], d0 = pw[3][0], d1 = pw[3][1];
    permlane32_swap(c0, d0); permlane32_swap(c1, d1);
    permlane16_swap(c0, d0); permlane16_swap(c1, d1);
    pf1 = __builtin_bit_cast(bf16x8, (uint32x4){c0, c1, d0, d1});
}

// Causal flash attention. 1024 blocks (XCD-swizzled). 4 waves/block; each wave
// owns TWO 16-row q-tiles from complementary q-blocks {j, 31-j}. K/V 64-key
// tiles staged into double-buffered LDS via global_load_lds (swizzled source);
// 2-phase pipeline, 1 barrier/iter.
__global__ __launch_bounds__(256) void attn_kernel(
    const ushort* __restrict__ Qb, const ushort* __restrict__ Kb,
    const ushort* __restrict__ Vt, ushort* __restrict__ Ob)
{
    __shared__ __align__(16) ushort Klds[2][4096];
    __shared__ __align__(16) ushort Vlds[2][4096];

    const int lane = threadIdx.x & 63;
    const int w    = threadIdx.x >> 6;
    const int l16  = lane & 15;
    const int g    = lane >> 4;

    const int bid = blockIdx.x;
    const int xcd = bid & 7, ii = bid >> 3;
    const int bh  = xcd * 8 + (ii >> 4);               // 8 (b,h) per XCD
    const int jlo = ii & 15;
    const int jhi = 31 - jlo;

    const int qr0_lo = jlo * 64 + w * 16;
    const int qr0_hi = jhi * 64 + w * 16;
    const int nt = jhi + 1;                            // 64-key tiles

    const ushort* QpL = Qb + ((size_t)bh * NSEQ + qr0_lo + l16) * DHEAD + 8 * g;
    const ushort* QpH = Qb + ((size_t)bh * NSEQ + qr0_hi + l16) * DHEAD + 8 * g;
    const bf16x8 qfL0 = *reinterpret_cast<const bf16x8*>(QpL);
    const bf16x8 qfL1 = *reinterpret_cast<const bf16x8*>(QpL + 32);
    const bf16x8 qfH0 = *reinterpret_cast<const bf16x8*>(QpH);
    const bf16x8 qfH1 = *reinterpret_cast<const bf16x8*>(QpH + 32);

    const ushort* Kg = Kb + (size_t)bh * (NSEQ * DHEAD);
    const ushort* Vg = Vt + (size_t)bh * (NSEQ * DHEAD);

    const int q0    = w * 2;
    const int srow  = lane >> 2;
    const int sswz8 = ((lane & 3) ^ ((lane >> 3) & 3)) * 8;
    const int cq8   = (g ^ ((l16 >> 1) & 3)) * 8;

    f32x4 oaccL[4] = {}, oaccH[4] = {};
    float mrunL = -1e30f, lsumL = 0.f, mrunH = -1e30f, lsumH = 0.f;

    #pragma unroll
    for (int i = 0; i < 2; ++i) {
        const int q = q0 + i;
        gload16(Kg + (size_t)((q & 3) * 16 + srow) * 64 + (q >> 2) * 32 + sswz8,
                &Klds[0][q * 512]);
        gload16(Vg + (size_t)(q >> 2) * 2048 + ((q & 3) * 16 + srow) * 32 + sswz8,
                &Vlds[0][q * 512]);
    }
    __syncthreads();

    for (int t = 0; t < nt; ++t) {
        const int cur = t & 1;
        if (t + 1 < nt) {
            const int kt1 = (t + 1) * 64;
            #pragma unroll
            for (int i = 0; i < 2; ++i) {
                const int q = q0 + i;
                gload16(Kg + (size_t)(kt1 + (q & 3) * 16 + srow) * 64 + (q >> 2) * 32 + sswz8,
                        &Klds[cur ^ 1][q * 512]);
                gload16(Vg + (size_t)kt1 * 64 + (q >> 2) * 2048 + ((q & 3) * 16 + srow) * 32 + sswz8,
                        &Vlds[cur ^ 1][q * 512]);
            }
        }
        const int kt = t * 64;
        bf16x8 kk[4][2];
        #pragma unroll
        for (int tt = 0; tt < 4; ++tt) {
            #pragma unroll
            for (int h = 0; h < 2; ++h)
                kk[tt][h] = *reinterpret_cast<const bf16x8*>(
                    &Klds[cur][h * 2048 + (16 * tt + l16) * 32 + cq8]);
        }
        bf16x8 pfH0, pfH1, pfL0, pfL1;
        attn_qk(kt, qr0_hi, l16, g, kk, qfH0, qfH1, oaccH, mrunH, lsumH, pfH0, pfH1);
        const bool doLo = (t <= jlo);
        if (doLo)
            attn_qk(kt, qr0_lo, l16, g, kk, qfL0, qfL1, oaccL, mrunL, lsumL, pfL0, pfL1);
        __builtin_amdgcn_s_setprio(1);
        #pragma unroll
        for (int dt = 0; dt < 4; ++dt) {
            const bf16x8 v0 = *reinterpret_cast<const bf16x8*>(
                &Vlds[cur][(dt * 16 + l16) * 32 + cq8]);
            const bf16x8 v1 = *reinterpret_cast<const bf16x8*>(
                &Vlds[cur][2048 + (dt * 16 + l16) * 32 + cq8]);
            oaccH[dt] = __builtin_amdgcn_mfma_f32_16x16x32_bf16(pfH0, v0, oaccH[dt], 0, 0, 0);
            oaccH[dt] = __builtin_amdgcn_mfma_f32_16x16x32_bf16(pfH1, v1, oaccH[dt], 0, 0, 0);
            if (doLo) {
                oaccL[dt] = __builtin_amdgcn_mfma_f32_16x16x32_bf16(pfL0, v0, oaccL[dt], 0, 0, 0);
                oaccL[dt] = __builtin_amdgcn_mfma_f32_16x16x32_bf16(pfL1, v1, oaccL[dt], 0, 0, 0);
            }
        }
        __builtin_amdgcn_s_setprio(0);
        __syncthreads();
    }

    const int bb = bh >> 4, h = bh & 15;
    {
        const float inv = 1.0f / red_sum_g(lsumH);     // cross-lane sum here
        float invj[4];
        #pragma unroll
        for (int jj = 0; jj < 4; ++jj) invj[jj] = __shfl(inv, 4 * g + jj);
        #pragma unroll
        for (int jj = 0; jj < 4; ++jj) {
            const size_t t = (size_t)bb * NSEQ + qr0_hi + 4 * g + jj;
            #pragma unroll
            for (int dt = 0; dt < 4; ++dt)
                Ob[t * DMODEL + h * DHEAD + dt * 16 + l16] = f32_bf16(oaccH[dt][jj] * invj[jj]);
        }
    }
    {
        const float inv = 1.0f / red_sum_g(lsumL);
        float invj[4];
        #pragma unroll
        for (int jj = 0; jj < 4; ++jj) invj[jj] = __shfl(inv, 4 * g + jj);
        #pragma unroll
        for (int jj = 0; jj < 4; ++jj) {
            const size_t t = (size_t)bb * NSEQ + qr0_lo + 4 * g + jj;
            #pragma unroll
            for (int dt = 0; dt < 4; ++dt)
                Ob[t * DMODEL + h * DHEAD + dt * 16 + l16] = f32_bf16(oaccL[dt][jj] * invj[jj]);
        }
    }
}

extern "C" void kernel_launch(void* const* d_in, const int* in_sizes, int n_in,
                              void* d_out, int out_size, void* d_ws, size_t ws_size,
                              hipStream_t stream)
{
    const float* x     = (const float*)d_in[0];
    const float* w_qkv = (const float*)d_in[1];
    const float* w_out = (const float*)d_in[2];
    const float* b_out = (const float*)d_in[3];
    float* out = (float*)d_out;

    char* ws = (char*)d_ws;
    ushort* x_bf   = (ushort*)(ws);                    // 16,777,216  (reused as attn out)
    ushort* wqkv_t = (ushort*)(ws + 16777216);         //  6,291,456
    ushort* wout_t = (ushort*)(ws + 23068672);         //  2,097,152
    ushort* q_bf   = (ushort*)(ws + 25165824);         // 16,777,216
    ushort* k_bf   = (ushort*)(ws + 41943040);         // 16,777,216
    ushort* vt_bf  = (ushort*)(ws + 58720256);         // 16,777,216 (V^T tiled)
    ushort* attn_bf = x_bf;

    fused_cvt_kernel<<<dim3(9216), dim3(256), 0, stream>>>(
        x, x_bf, w_qkv, wqkv_t, w_out, wout_t);

    gemm_bt<0, NQKV / 128><<<dim3((NQKV / 128) * (TOKENS / 128)), dim3(256), 0, stream>>>(
        x_bf, wqkv_t, q_bf, k_bf, vt_bf, nullptr, nullptr);

    attn_kernel<<<dim3(1024), dim3(256), 0, stream>>>(q_bf, k_bf, vt_bf, attn_bf);

    gemm_bt<1, DMODEL / 128><<<dim3((DMODEL / 128) * (TOKENS / 128)), dim3(256), 0, stream>>>(
        attn_bf, wout_t, nullptr, nullptr, nullptr, out, b_out);
}